// Round 6
// baseline (452.265 us; speedup 1.0000x reference)
//
#include <hip/hip_runtime.h>
#include <math.h>

#define T_TOK 8192
#define D_DIM 7168
#define E_EXP 256
#define TOPKN 8
#define NGRP 8
#define TOPG 4
#define ROUTE_SCALEF 2.5f

#define KSPLIT 8
#define KPER (D_DIM / KSPLIT)    // 896
#define NTILE (KPER / 32)        // 28
#define BM 128
#define BN 256

typedef _Float16 f16;
typedef f16 f16x8 __attribute__((ext_vector_type(8)));
typedef float f32x4 __attribute__((ext_vector_type(4)));

// ---------------- kernel 1: W -> {64*hi, 64*lo} f16, pre-swizzled slot layout ----
// LDS read swizzle is chunk^=(row>>1)&3; bake the same involution into the global
// image so global_load_lds (linear dest) + swizzled ds_read round-trips (rule 21).
__global__ __launch_bounds__(256)
void split_w(const float* __restrict__ W, f16* __restrict__ Wh, f16* __restrict__ Wl) {
  const int e  = blockIdx.x;
  const int se = (e >> 1) & 3;
  for (int s = threadIdx.x; s < D_DIM / 8; s += 256) {
    const int t = s >> 2, c = s & 3;
    const int kin  = t * 32 + ((c ^ se) << 3);
    const int kout = t * 32 + (c << 3);
    const float4 v0 = *(const float4*)(W + (size_t)e * D_DIM + kin);
    const float4 v1 = *(const float4*)(W + (size_t)e * D_DIM + kin + 4);
    const float pe[8] = {v0.x, v0.y, v0.z, v0.w, v1.x, v1.y, v1.z, v1.w};
    f16x8 h, l;
#pragma unroll
    for (int m = 0; m < 8; ++m) {
      const float hf = (float)(f16)pe[m];
      h[m] = (f16)(hf * 64.0f);              // exact exponent shift
      l[m] = (f16)((pe[m] - hf) * 64.0f);
    }
    *(f16x8*)(Wh + (size_t)e * D_DIM + kout) = h;
    *(f16x8*)(Wl + (size_t)e * D_DIM + kout) = l;
  }
}

// ---------------- kernel 2: partial[ks] = (64X)*(64W)^T via 3-chain f16 MFMA ----
// A: direct global->register fragments (no LDS round-trip). B: gload_lds
// double-buffer. One barrier per K-tile; every load is issued a full compute
// phase before the barrier that drains it -> latency hidden under MFMA.
__device__ __forceinline__ void gload_lds16(const void* g, void* l) {
  __builtin_amdgcn_global_load_lds(
      (const __attribute__((address_space(1))) unsigned int*)g,
      (__attribute__((address_space(3))) unsigned int*)l, 16, 0, 0);
}

__device__ __forceinline__ void cvt8(const float4 a, const float4 b, f16x8& h, f16x8& l) {
  const float pe[8] = {a.x, a.y, a.z, a.w, b.x, b.y, b.z, b.w};
#pragma unroll
  for (int m = 0; m < 8; ++m) {
    const float hf = (float)(f16)pe[m];
    h[m] = (f16)(hf * 64.0f);
    l[m] = (f16)((pe[m] - hf) * 64.0f);
  }
}

__global__ __launch_bounds__(512, 2)
void gate_gemm(const float* __restrict__ X, const f16* __restrict__ Wh,
               const f16* __restrict__ Wl, float* __restrict__ partial) {
  __shared__ f16 BhL[2][BN][32];   // 32 KB
  __shared__ f16 BlL[2][BN][32];   // 32 KB

  const int tid  = threadIdx.x;
  const int lane = tid & 63;
  const int wid  = tid >> 6;               // 0..7
  // bid = mb*8 + ks: XCD (= bid%8) hosts one ks -> its 1.84 MB B-slice is
  // L2-resident per XCD; X slices are unique per block -> X read once.
  const int mb = blockIdx.x >> 3, ks = blockIdx.x & 7;
  const int kbase = ks * KPER;

  // wave grid 4M x 2N: wave-tile 32 x 128
  const int wm = (wid >> 1) * 32;
  const int wn = (wid & 1) * 128;
  const int fr  = lane & 15;
  const int kch = lane >> 4;               // 0..3

  // A fragment pointers: lane holds rows (wm+fr, wm+16+fr), k-chunk kch*8
  const float* pA0 = X + (size_t)(mb * BM + wm + fr) * D_DIM + kbase + kch * 8;
  const float* pA1 = pA0 + (size_t)16 * D_DIM;

  // B stage source (pre-swizzled image); wave stages rows [32w, 32w+32)
  const f16* sWh = Wh + (size_t)(wid * 32 + (lane >> 2)) * D_DIM + kbase + ((lane & 3) << 3);
  const f16* sWl = Wl + (size_t)(wid * 32 + (lane >> 2)) * D_DIM + kbase + ((lane & 3) << 3);

  const int rdoff = (kch << 3) ^ (((fr >> 1) & 3) << 3);   // swizzled f16 offset

  f32x4 acc[2][8];
#pragma unroll
  for (int i = 0; i < 2; ++i)
#pragma unroll
    for (int j = 0; j < 8; ++j) acc[i][j] = f32x4{0.f, 0.f, 0.f, 0.f};

  // prologue: A(0) regs + B(0) -> buf0
  float4 pc0 = *(const float4*)(pA0);
  float4 pc1 = *(const float4*)(pA0 + 4);
  float4 pc2 = *(const float4*)(pA1);
  float4 pc3 = *(const float4*)(pA1 + 4);
  gload_lds16(sWh,                      &BhL[0][wid * 32][0]);
  gload_lds16(sWh + (size_t)16 * D_DIM, &BhL[0][wid * 32 + 16][0]);
  gload_lds16(sWl,                      &BlL[0][wid * 32][0]);
  gload_lds16(sWl + (size_t)16 * D_DIM, &BlL[0][wid * 32 + 16][0]);
  float4 pn0, pn1, pn2, pn3;
  __syncthreads();

  auto phase = [&](int kcN, int bufC, int bufN,
                   const float4& c0, const float4& c1, const float4& c2, const float4& c3,
                   float4& n0, float4& n1, float4& n2, float4& n3) {
    // issue next-tile A (regs) and B (gload_lds) first: in flight across the
    // whole compute phase, drained cheaply at the ending barrier
    n0 = *(const float4*)(pA0 + kcN);
    n1 = *(const float4*)(pA0 + kcN + 4);
    n2 = *(const float4*)(pA1 + kcN);
    n3 = *(const float4*)(pA1 + kcN + 4);
    gload_lds16(sWh + kcN,                      &BhL[bufN][wid * 32][0]);
    gload_lds16(sWh + kcN + (size_t)16 * D_DIM, &BhL[bufN][wid * 32 + 16][0]);
    gload_lds16(sWl + kcN,                      &BlL[bufN][wid * 32][0]);
    gload_lds16(sWl + kcN + (size_t)16 * D_DIM, &BlL[bufN][wid * 32 + 16][0]);
    // convert current A (loaded a full tile ago -> no wait)
    f16x8 ah0, al0, ah1, al1;
    cvt8(c0, c1, ah0, al0);
    cvt8(c2, c3, ah1, al1);
#pragma unroll
    for (int j = 0; j < 8; ++j) {
      const f16x8 bh = *(const f16x8*)&BhL[bufC][wn + j * 16 + fr][rdoff];
      const f16x8 bl = *(const f16x8*)&BlL[bufC][wn + j * 16 + fr][rdoff];
      acc[0][j] = __builtin_amdgcn_mfma_f32_16x16x32_f16(ah0, bh, acc[0][j], 0, 0, 0);
      acc[1][j] = __builtin_amdgcn_mfma_f32_16x16x32_f16(ah1, bh, acc[1][j], 0, 0, 0);
      acc[0][j] = __builtin_amdgcn_mfma_f32_16x16x32_f16(ah0, bl, acc[0][j], 0, 0, 0);
      acc[1][j] = __builtin_amdgcn_mfma_f32_16x16x32_f16(ah1, bl, acc[1][j], 0, 0, 0);
      acc[0][j] = __builtin_amdgcn_mfma_f32_16x16x32_f16(al0, bh, acc[0][j], 0, 0, 0);
      acc[1][j] = __builtin_amdgcn_mfma_f32_16x16x32_f16(al1, bh, acc[1][j], 0, 0, 0);
    }
    __syncthreads();
  };

#pragma unroll 1
  for (int kt = 0; kt < NTILE; kt += 2) {
    const int kc1 = (kt + 1) * 32;
    const int kc2 = ((kt + 2 < NTILE) ? (kt + 2) : (NTILE - 1)) * 32;  // tail clamp
    phase(kc1, 0, 1, pc0, pc1, pc2, pc3, pn0, pn1, pn2, pn3);  // tile kt
    phase(kc2, 1, 0, pn0, pn1, pn2, pn3, pc0, pc1, pc2, pc3);  // tile kt+1
  }

  // epilogue: unscale (operands each *64 -> acc *4096); C/D: col=lane&15, row=(lane>>4)*4+r
  const float s = 1.0f / 4096.0f;
  float* pout = partial + (size_t)ks * T_TOK * E_EXP;
  const int orow = mb * BM + wm + (lane >> 4) * 4;
  const int ocol = wn + fr;
#pragma unroll
  for (int i = 0; i < 2; ++i)
#pragma unroll
    for (int j = 0; j < 8; ++j) {
      const f32x4 v = acc[i][j] * s;
#pragma unroll
      for (int r = 0; r < 4; ++r)
        pout[(size_t)(orow + i * 16 + r) * E_EXP + ocol + j * 16] = v[r];
    }
}

// ---------------- kernel 3: fused reduce + sigmoid + routing, one wave/token ----
__global__ __launch_bounds__(256)
void gate_route(const float* __restrict__ partial, const float* __restrict__ bias,
                float* __restrict__ wout, float* __restrict__ iout, int ksplit) {
  const int t    = (blockIdx.x * 256 + threadIdx.x) >> 6;
  const int lane = threadIdx.x & 63;

  // reduce K-split partials: lane owns experts 4*lane .. 4*lane+3
  float sx = 0.f, sy = 0.f, sz = 0.f, sw = 0.f;
  for (int ks = 0; ks < ksplit; ++ks) {
    const float4 p = *(const float4*)(partial + ((size_t)ks * T_TOK + t) * E_EXP + (lane << 2));
    sx += p.x; sy += p.y; sz += p.z; sw += p.w;
  }
  const float o0 = 1.f / (1.f + expf(-sx));
  const float o1 = 1.f / (1.f + expf(-sy));
  const float o2 = 1.f / (1.f + expf(-sz));
  const float o3 = 1.f / (1.f + expf(-sw));
  const float4 bv4 = *(const float4*)(bias + (lane << 2));
  const float b0 = o0 + bv4.x, b1 = o1 + bv4.y, b2 = o2 + bv4.z, b3 = o3 + bv4.w;

  // top-2 within lane, then merge across the 8 lanes of this group
  const float ma = fmaxf(b0, b1), mi = fminf(b0, b1);
  const float mb_ = fmaxf(b2, b3), mn = fminf(b2, b3);
  float m1 = fmaxf(ma, mb_);
  float m2 = fmaxf(fminf(ma, mb_), fmaxf(mi, mn));
#pragma unroll
  for (int msk = 1; msk <= 4; msk <<= 1) {
    const float p1 = __shfl_xor(m1, msk);
    const float p2 = __shfl_xor(m2, msk);
    const float nm1 = fmaxf(m1, p1);
    const float nm2 = fmaxf(fminf(m1, p1), fmaxf(m2, p2));
    m1 = nm1; m2 = nm2;
  }
  const float gs = m1 + m2;

  // top-4 groups (ties -> lowest group idx)
  float ga[8];
#pragma unroll
  for (int g = 0; g < 8; ++g) ga[g] = __shfl(gs, g * 8);
  int keepmask = 0;
#pragma unroll
  for (int r = 0; r < TOPG; ++r) {
    float bvv = -INFINITY; int bg = 0;
#pragma unroll
    for (int g = 0; g < NGRP; ++g) {
      const bool better = !((keepmask >> g) & 1) && (ga[g] > bvv);
      bvv = better ? ga[g] : bvv;
      bg  = better ? g : bg;
    }
    keepmask |= 1 << bg;
  }

  const bool kept = (keepmask >> (lane >> 3)) & 1;
  const float c0 = kept ? b0 : -INFINITY;
  const float c1 = kept ? b1 : -INFINITY;
  const float c2 = kept ? b2 : -INFINITY;
  const float c3 = kept ? b3 : -INFINITY;

  // 8 rounds of wave-wide argmax (max value, ties -> min expert index)
  int used = 0;
  float sum = 0.f, selw = 0.f;
  int seli = 0;
#pragma unroll
  for (int r = 0; r < TOPKN; ++r) {
    float bv_ = -INFINITY; int bi_ = 0x7FFFFFFF; float bo_ = 0.f;
    { const bool ok = !(used & 1) && (c0 > bv_); bv_ = ok ? c0 : bv_; bi_ = ok ? (lane << 2)     : bi_; bo_ = ok ? o0 : bo_; }
    { const bool ok = !(used & 2) && (c1 > bv_); bv_ = ok ? c1 : bv_; bi_ = ok ? (lane << 2) | 1 : bi_; bo_ = ok ? o1 : bo_; }
    { const bool ok = !(used & 4) && (c2 > bv_); bv_ = ok ? c2 : bv_; bi_ = ok ? (lane << 2) | 2 : bi_; bo_ = ok ? o2 : bo_; }
    { const bool ok = !(used & 8) && (c3 > bv_); bv_ = ok ? c3 : bv_; bi_ = ok ? (lane << 2) | 3 : bi_; bo_ = ok ? o3 : bo_; }
#pragma unroll
    for (int m = 1; m < 64; m <<= 1) {
      const float vp = __shfl_xor(bv_, m);
      const int   ip = __shfl_xor(bi_, m);
      const float op = __shfl_xor(bo_, m);
      const bool take = (vp > bv_) || (vp == bv_ && ip < bi_);
      bv_ = take ? vp : bv_; bi_ = take ? ip : bi_; bo_ = take ? op : bo_;
    }
    sum += bo_;
    if (lane == r) { selw = bo_; seli = bi_; }
    if ((bi_ >> 2) == lane) used |= 1 << (bi_ & 3);
  }

  if (lane < TOPKN) {
    wout[(size_t)t * TOPKN + lane] = (selw / sum) * ROUTE_SCALEF;
    iout[(size_t)t * TOPKN + lane] = (float)seli;
  }
}

extern "C" void kernel_launch(void* const* d_in, const int* in_sizes, int n_in,
                              void* d_out, int out_size, void* d_ws, size_t ws_size,
                              hipStream_t stream) {
  const float* x = (const float*)d_in[0];
  const float* w = (const float*)d_in[1];
  const float* b = (const float*)d_in[2];
  float* out = (float*)d_out;

  // ws layout (74.5 MB, confirmed fits in round 3): Wh | Wl | partial[8][T][E]
  f16* Wh = (f16*)d_ws;
  f16* Wl = Wh + (size_t)E_EXP * D_DIM;
  float* partial = (float*)(Wl + (size_t)E_EXP * D_DIM);

  split_w<<<E_EXP, 256, 0, stream>>>(w, Wh, Wl);

  gate_gemm<<<(T_TOK / BM) * KSPLIT, 512, 0, stream>>>(x, Wh, Wl, partial);

  float* wout = out;
  float* iout = out + (size_t)T_TOK * TOPKN;
  gate_route<<<T_TOK / 4, 256, 0, stream>>>(partial, b, wout, iout, KSPLIT);
}